// Round 15
// baseline (154.859 us; speedup 1.0000x reference)
//
#include <hip/hip_runtime.h>

#define LSEQ 4096
#define DH 64
#define NBATCH 4
#define QB 32                  // q-rows per tile (2 MFMA row-tiles)
#define NQT (LSEQ / QB)        // 128 q-tiles per batch
#define QTPB_S 4               // q-tiles per block, sums kernel
#define NQG_S (NQT / QTPB_S)   // 32
#define QTPB_F 8               // q-tiles per block, fused kernel
#define NQG_F (NQT / QTPB_F)   // 16
#define NROW (NBATCH * LSEQ)   // 16384
#define NSLICE 8
#define SLW (LSEQ / NSLICE)    // 512 cols per slice
#define PADT (SLW + 8)         // u16 row stride 1040 B

typedef unsigned short u16;
typedef __bf16 bf16x8 __attribute__((ext_vector_type(8)));
typedef float f32x4 __attribute__((ext_vector_type(4)));
typedef u16 u16x4 __attribute__((ext_vector_type(4), may_alias));

static __device__ __forceinline__ u16 f2bf(float f) {
  union { float f; unsigned u; } v; v.f = f;
  unsigned r = v.u + 0x7FFFu + ((v.u >> 16) & 1u);   // RNE
  return (u16)(r >> 16);
}
static __device__ __forceinline__ float bf2f(u16 s) {
  union { unsigned u; float f; } v; v.u = ((unsigned)s) << 16;
  return v.f;
}
static __device__ __forceinline__ float wsum(float v) {
#pragma unroll
  for (int off = 32; off > 0; off >>= 1) v += __shfl_xor(v, off, 64);
  return v;
}
static __device__ __forceinline__ int xcd_swz(int bid, int shift) {  // bijective, nwg%8==0
  return ((bid & 7) << shift) | (bid >> 3);
}

// ---------------- Kernel 1: QKV projection (q scaled by 0.125*log2e for exp2) ----------
__global__ __launch_bounds__(256) void qkv_kernel(
    const float* __restrict__ qry, const float* __restrict__ key, const float* __restrict__ val,
    const float* __restrict__ Wq, const float* __restrict__ Wk, const float* __restrict__ Wv,
    u16* __restrict__ qb, u16* __restrict__ kb, u16* __restrict__ vtb) {
  __shared__ float w_lds[64 * 65];
  __shared__ float in_lds[64 * 65];
  __shared__ u16 v_lds[64 * 72];
  const int bid = blockIdx.x;
  const int b = bid >> 6;
  const int lbase = (bid & 63) << 6;
  const int tid = threadIdx.x;
  const int wv = tid >> 6, ln = tid & 63;

  for (int m = 0; m < 3; ++m) {
    const float* X = (m == 0) ? qry : (m == 1) ? key : val;
    const float* W = (m == 0) ? Wq : (m == 1) ? Wk : Wv;
    const size_t xbase = ((size_t)(b * LSEQ + lbase)) * DH;
    for (int i = tid; i < 4096; i += 256) {
      w_lds[(i >> 6) * 65 + (i & 63)] = W[i];
      in_lds[(i >> 6) * 65 + (i & 63)] = X[xbase + i];
    }
    __syncthreads();
    for (int rr = 0; rr < 16; ++rr) {
      const int row = wv * 16 + rr;
      float acc = 0.f;
#pragma unroll
      for (int d = 0; d < 64; ++d) acc += in_lds[row * 65 + d] * w_lds[ln * 65 + d];
      const size_t orow = ((size_t)(b * LSEQ + lbase + row)) * DH + ln;
      if (m == 0)      qb[orow] = f2bf(acc * 0.1803368801f); // 1/8 * log2(e): exp2(q.k)=e^s
      else if (m == 1) kb[orow] = f2bf(acc);
      else             v_lds[row * 72 + ln] = f2bf(acc);
    }
    __syncthreads();
  }
  // transposed V write: vtb[b][d][l]
  for (int i = tid; i < 4096; i += 256) {
    const int dd = i >> 6, lc = i & 63;
    vtb[((size_t)(b * DH + dd)) * LSEQ + lbase + lc] = v_lds[lc * 72 + dd];
  }
}

// ---- Kernel 2a: REGISTER-ONLY partial rowsums; K resident across 4 q-tiles ------------
__global__ __launch_bounds__(256, 4) void sums_kernel(
    const u16* __restrict__ qb, const u16* __restrict__ kb,
    float* __restrict__ rows_part) {
  __shared__ float red[4][QB];

  const int bid = xcd_swz(blockIdx.x, 7);          // 1024 blocks
  const int qg = bid & (NQG_S - 1);
  const int sl = (bid >> 5) & (NSLICE - 1);
  const int b  = bid >> 8;
  const int c0 = sl * SLW;
  const int tid = threadIdx.x;
  const int w = tid >> 6;
  const int l = tid & 63;
  const int lo = l & 15, g = l >> 4;

  const int cw = w * (SLW / 4);

  bf16x8 kr0[8], kr1[8];
#pragma unroll
  for (int t = 0; t < 8; ++t) {
    const size_t koff = ((size_t)(b * LSEQ + c0 + cw + t * 16 + lo)) * DH + 8 * g;
    kr0[t] = *reinterpret_cast<const bf16x8*>(kb + koff);
    kr1[t] = *reinterpret_cast<const bf16x8*>(kb + koff + 32);
  }

  for (int qi = 0; qi < QTPB_S; ++qi) {
    const int qbase = (qg * QTPB_S + qi) << 5;
    bf16x8 qa0[2], qa1[2];
#pragma unroll
    for (int rt = 0; rt < 2; ++rt) {
      const size_t qoff = ((size_t)(b * LSEQ + qbase + rt * 16 + lo)) * DH + 8 * g;
      qa0[rt] = *reinterpret_cast<const bf16x8*>(qb + qoff);
      qa1[rt] = *reinterpret_cast<const bf16x8*>(qb + qoff + 32);
    }

    float lsum[2][4] = {{0.f, 0.f, 0.f, 0.f}, {0.f, 0.f, 0.f, 0.f}};
#pragma unroll
    for (int t = 0; t < 8; ++t) {
#pragma unroll
      for (int rt = 0; rt < 2; ++rt) {
        f32x4 acc = {0.f, 0.f, 0.f, 0.f};
        acc = __builtin_amdgcn_mfma_f32_16x16x32_bf16(qa0[rt], kr0[t], acc, 0, 0, 0);
        acc = __builtin_amdgcn_mfma_f32_16x16x32_bf16(qa1[rt], kr1[t], acc, 0, 0, 0);
#pragma unroll
        for (int i = 0; i < 4; ++i) lsum[rt][i] += exp2f(acc[i]);
      }
    }
#pragma unroll
    for (int rt = 0; rt < 2; ++rt)
#pragma unroll
      for (int i = 0; i < 4; ++i) {
#pragma unroll
        for (int off = 1; off < 16; off <<= 1)
          lsum[rt][i] += __shfl_xor(lsum[rt][i], off, 64);
      }
    if (lo == 0) {
#pragma unroll
      for (int rt = 0; rt < 2; ++rt)
#pragma unroll
        for (int i = 0; i < 4; ++i) red[w][rt * 16 + 4 * g + i] = lsum[rt][i];
    }
    __syncthreads();
    if (tid < QB)
      rows_part[(size_t)sl * NROW + b * LSEQ + qbase + tid] =
          red[0][tid] + red[1][tid] + red[2][tid] + red[3][tid];
    __syncthreads();                     // red consumed before next q-tile
  }
}

// ---------------- Kernel 2b: rowinv = 1 / sum of slice partials ------------------------
__global__ __launch_bounds__(256) void rinv_kernel(
    const float* __restrict__ rows_part, float* __restrict__ rowinv_g) {
  const int i = blockIdx.x * 256 + threadIdx.x;    // 16384 rows
  float s = 0.f;
#pragma unroll
  for (int sl = 0; sl < NSLICE; ++sl) s += rows_part[(size_t)sl * NROW + i];
  rowinv_g[i] = 1.0f / s;
}

// ---- Kernel 2c: FUSED p-tile -> {PV partials + streaming att write} -------------------
// QTPB_F=8 q-tiles per block (grid 512); s_tile DOUBLE-BUFFERED -> 1 barrier per q-tile.
__global__ __launch_bounds__(256, 2) void fused_kernel(
    const u16* __restrict__ qb, const u16* __restrict__ kb, const u16* __restrict__ vtb,
    const float* __restrict__ rowinv_g, float* __restrict__ att,
    float* __restrict__ pv_part) {
  __shared__ u16 s_tile[2][QB * PADT];   // 2 x 33,280 B = 66,560 B
  __shared__ float s_rinv[2][QB];

  const int bid = xcd_swz(blockIdx.x, 6);          // 512 blocks
  const int qg = bid & (NQG_F - 1);
  const int sl = (bid >> 4) & (NSLICE - 1);
  const int b  = bid >> 7;
  const int c0 = sl * SLW;
  const int tid = threadIdx.x;
  const int w = tid >> 6;
  const int l = tid & 63;
  const int lo = l & 15, g = l >> 4;

  const int cw = w * (SLW / 4);
  const int dbase = w * 16;

  // --- preload K (64 VGPR) + V (64 VGPR), block-resident across 8 q-tiles ---
  bf16x8 kr0[8], kr1[8];
#pragma unroll
  for (int t = 0; t < 8; ++t) {
    const size_t koff = ((size_t)(b * LSEQ + c0 + cw + t * 16 + lo)) * DH + 8 * g;
    kr0[t] = *reinterpret_cast<const bf16x8*>(kb + koff);
    kr1[t] = *reinterpret_cast<const bf16x8*>(kb + koff + 32);
  }
  const size_t vrow = ((size_t)(b * DH + dbase + lo)) * LSEQ;
  bf16x8 vr[16];
#pragma unroll
  for (int t = 0; t < 16; ++t)
    vr[t] = *reinterpret_cast<const bf16x8*>(vtb + vrow + c0 + t * 32 + 8 * g);

  for (int qi = 0; qi < QTPB_F; ++qi) {
    const int buf = qi & 1;
    const int qbase = (qg * QTPB_F + qi) << 5;
    bf16x8 qa0[2], qa1[2];
#pragma unroll
    for (int rt = 0; rt < 2; ++rt) {
      const size_t qoff = ((size_t)(b * LSEQ + qbase + rt * 16 + lo)) * DH + 8 * g;
      qa0[rt] = *reinterpret_cast<const bf16x8*>(qb + qoff);
      qa1[rt] = *reinterpret_cast<const bf16x8*>(qb + qoff + 32);
    }
    if (tid < QB) s_rinv[buf][tid] = rowinv_g[b * LSEQ + qbase + tid];

    // --- Phase 1: QK^T + exp2 into s_tile[buf] ---
    // Safe w/o leading barrier: last readers of s_tile[buf] were phase2(qi-2),
    // ordered before barrier(qi-1) for every wave.
#pragma unroll
    for (int t = 0; t < 8; ++t) {
#pragma unroll
      for (int rt = 0; rt < 2; ++rt) {
        f32x4 acc = {0.f, 0.f, 0.f, 0.f};
        acc = __builtin_amdgcn_mfma_f32_16x16x32_bf16(qa0[rt], kr0[t], acc, 0, 0, 0);
        acc = __builtin_amdgcn_mfma_f32_16x16x32_bf16(qa1[rt], kr1[t], acc, 0, 0, 0);
#pragma unroll
        for (int i = 0; i < 4; ++i)
          s_tile[buf][(rt * 16 + 4 * g + i) * PADT + cw + t * 16 + lo] =
              f2bf(exp2f(acc[i]));
      }
    }
    __syncthreads();                     // s_tile[buf] + s_rinv[buf] ready

    // --- Phase 2a: PV partials (V register-resident) ---
    f32x4 pv0[2] = {{0.f, 0.f, 0.f, 0.f}, {0.f, 0.f, 0.f, 0.f}};
    f32x4 pv1[2] = {{0.f, 0.f, 0.f, 0.f}, {0.f, 0.f, 0.f, 0.f}};
#pragma unroll
    for (int t = 0; t < 8; ++t) {
#pragma unroll
      for (int rt = 0; rt < 2; ++rt) {
        const bf16x8 pa0 = *reinterpret_cast<const bf16x8*>(
            s_tile[buf] + (rt * 16 + lo) * PADT + t * 64 + 8 * g);
        pv0[rt] = __builtin_amdgcn_mfma_f32_16x16x32_bf16(pa0, vr[2 * t], pv0[rt], 0, 0, 0);
        const bf16x8 pa1 = *reinterpret_cast<const bf16x8*>(
            s_tile[buf] + (rt * 16 + lo) * PADT + t * 64 + 32 + 8 * g);
        pv1[rt] = __builtin_amdgcn_mfma_f32_16x16x32_bf16(pa1, vr[2 * t + 1], pv1[rt], 0, 0, 0);
      }
    }
#pragma unroll
    for (int rt = 0; rt < 2; ++rt)
#pragma unroll
      for (int i = 0; i < 4; ++i) {
        const int r = rt * 16 + 4 * g + i;
        pv_part[((size_t)sl * NROW + b * LSEQ + qbase + r) * DH + dbase + lo] =
            pv0[rt][i] + pv1[rt][i];
      }

    // --- Phase 2b: streaming normalized att store ---
    float* attbase = att + ((size_t)(b * LSEQ + qbase)) * LSEQ + c0;
#pragma unroll
    for (int it = 0; it < 16; ++it) {
      const int u = it * 256 + tid;      // 0..4095
      const int row = u >> 7;            // wave-uniform
      const int c4 = (u & 127) * 4;
      const u16x4 p4 = *reinterpret_cast<const u16x4*>(s_tile[buf] + row * PADT + c4);
      const float ri = s_rinv[buf][row];
      f32x4 o;
      o[0] = bf2f(p4[0]) * ri; o[1] = bf2f(p4[1]) * ri;
      o[2] = bf2f(p4[2]) * ri; o[3] = bf2f(p4[3]) * ri;
      __builtin_nontemporal_store(o, reinterpret_cast<f32x4*>(attbase + (size_t)row * LSEQ + c4));
    }
    // no trailing barrier: next iteration writes the OTHER buffer
  }
}

// ------- Kernel 3: (sum pv_part)*rinv + residual LN1 -> MLP -> residual LN2 ------------
__global__ __launch_bounds__(256) void post_kernel(
    const float* __restrict__ pv_part, const float* __restrict__ rowinv_g,
    const float* __restrict__ qry,
    const float* __restrict__ ln1g, const float* __restrict__ ln1b,
    const float* __restrict__ W1, const float* __restrict__ b1,
    const float* __restrict__ W2, const float* __restrict__ b2,
    const float* __restrict__ ln2g, const float* __restrict__ ln2b,
    float* __restrict__ out) {
  __shared__ float w1_lds[64 * 65];
  __shared__ float w2_lds[64 * 65];
  __shared__ float vg1[64], vb1l[64], vbi1[64], vbi2[64], vg2[64], vb2l[64];
  __shared__ float o1_buf[4][64];
  __shared__ float h_buf[4][64];
  const int bid = blockIdx.x;
  const int b = bid >> 8;
  const int lbase = (bid & 255) << 4;
  const int tid = threadIdx.x, wv = tid >> 6, ln = tid & 63;

  for (int i = tid; i < 4096; i += 256) {
    w1_lds[(i >> 6) * 65 + (i & 63)] = W1[i];
    w2_lds[(i >> 6) * 65 + (i & 63)] = W2[i];
  }
  if (tid < 64) {
    vg1[tid] = ln1g[tid]; vb1l[tid] = ln1b[tid];
    vbi1[tid] = b1[tid];  vbi2[tid] = b2[tid];
    vg2[tid] = ln2g[tid]; vb2l[tid] = ln2b[tid];
  }
  __syncthreads();

  for (int rr = 0; rr < 4; ++rr) {
    const int row = wv * 4 + rr;
    const size_t rowg = (size_t)b * LSEQ + lbase + row;
    const size_t gr = rowg * DH;
    float x = 0.f;
#pragma unroll
    for (int sl = 0; sl < NSLICE; ++sl) x += pv_part[((size_t)sl * NROW + rowg) * DH + ln];
    x = x * rowinv_g[rowg] + qry[gr + ln];
    float mu = wsum(x) * (1.f / 64.f);
    float dx = x - mu;
    float var = wsum(dx * dx) * (1.f / 64.f);
    const float o1 = dx * rsqrtf(var + 1e-6f) * vg1[ln] + vb1l[ln];
    o1_buf[wv][ln] = o1;
    float a1 = vbi1[ln];
#pragma unroll
    for (int d = 0; d < 64; ++d) a1 += o1_buf[wv][d] * w1_lds[ln * 65 + d];
    const float h = fmaxf(a1, 0.f);
    h_buf[wv][ln] = h;
    float a2 = vbi2[ln];
#pragma unroll
    for (int d = 0; d < 64; ++d) a2 += h_buf[wv][d] * w2_lds[ln * 65 + d];
    const float y = o1 + a2;
    mu = wsum(y) * (1.f / 64.f);
    const float dy = y - mu;
    var = wsum(dy * dy) * (1.f / 64.f);
    out[gr + ln] = dy * rsqrtf(var + 1e-6f) * vg2[ln] + vb2l[ln];
  }
}

extern "C" void kernel_launch(void* const* d_in, const int* in_sizes, int n_in,
                              void* d_out, int out_size, void* d_ws, size_t ws_size,
                              hipStream_t stream) {
  const float* qry = (const float*)d_in[0];
  const float* key = (const float*)d_in[1];
  const float* val = (const float*)d_in[2];
  const float* Wq  = (const float*)d_in[3];
  const float* Wk  = (const float*)d_in[4];
  const float* Wv  = (const float*)d_in[5];
  const float* g1  = (const float*)d_in[6];
  const float* bb1 = (const float*)d_in[7];
  const float* W1  = (const float*)d_in[8];
  const float* b1  = (const float*)d_in[9];
  const float* W2  = (const float*)d_in[10];
  const float* b2  = (const float*)d_in[11];
  const float* g2  = (const float*)d_in[12];
  const float* bb2 = (const float*)d_in[13];

  u16* qb  = (u16*)d_ws;                         // 2 MB
  u16* kb  = qb + (size_t)NROW * DH;             // 2 MB
  u16* vtb = kb + (size_t)NROW * DH;             // 2 MB (transposed [B][D][L])
  float* rows_part = (float*)(vtb + (size_t)NROW * DH);  // 512 KB
  float* rowinv_g  = rows_part + (size_t)NSLICE * NROW;  // 64 KB
  float* pv_part   = rowinv_g + NROW;            // 33.5 MB
  float* out = (float*)d_out;                    // [B,L,D] f32
  float* att = out + (size_t)NROW * DH;          // [B,L,L] f32

  qkv_kernel<<<dim3(256), dim3(256), 0, stream>>>(qry, key, val, Wq, Wk, Wv, qb, kb, vtb);
  sums_kernel<<<dim3(NBATCH * NSLICE * NQG_S), dim3(256), 0, stream>>>(qb, kb, rows_part);
  rinv_kernel<<<dim3(NROW / 256), dim3(256), 0, stream>>>(rows_part, rowinv_g);
  fused_kernel<<<dim3(NBATCH * NSLICE * NQG_F), dim3(256), 0, stream>>>(
      qb, kb, vtb, rowinv_g, att, pv_part);
  post_kernel<<<dim3(NBATCH * 256), dim3(256), 0, stream>>>(
      pv_part, rowinv_g, qry, g1, bb1, W1, b1, W2, b2, g2, bb2, out);
}

// Round 16
// 142.599 us; speedup vs baseline: 1.0860x; 1.0860x over previous
//
#include <hip/hip_runtime.h>

#define LSEQ 4096
#define DH 64
#define NBATCH 4
#define QB 32                  // q-rows per tile (2 MFMA row-tiles)
#define NQT (LSEQ / QB)        // 128 q-tiles per batch
#define QTPB_S 8               // q-tiles per block, sums kernel
#define NQG_S (NQT / QTPB_S)   // 16
#define QTPB_F 4               // q-tiles per block, fused kernel (R14 proven)
#define NQG_F (NQT / QTPB_F)   // 32
#define NROW (NBATCH * LSEQ)   // 16384
#define NSLICE 8
#define SLW (LSEQ / NSLICE)    // 512 cols per slice
#define PADT (SLW + 8)         // u16 row stride 1040 B

typedef unsigned short u16;
typedef __bf16 bf16x8 __attribute__((ext_vector_type(8)));
typedef float f32x4 __attribute__((ext_vector_type(4)));
typedef u16 u16x4 __attribute__((ext_vector_type(4), may_alias));

static __device__ __forceinline__ u16 f2bf(float f) {
  union { float f; unsigned u; } v; v.f = f;
  unsigned r = v.u + 0x7FFFu + ((v.u >> 16) & 1u);   // RNE
  return (u16)(r >> 16);
}
static __device__ __forceinline__ float bf2f(u16 s) {
  union { unsigned u; float f; } v; v.u = ((unsigned)s) << 16;
  return v.f;
}
static __device__ __forceinline__ float wsum(float v) {
#pragma unroll
  for (int off = 32; off > 0; off >>= 1) v += __shfl_xor(v, off, 64);
  return v;
}
static __device__ __forceinline__ int xcd_swz(int bid, int shift) {  // bijective, nwg%8==0
  return ((bid & 7) << shift) | (bid >> 3);
}

// -------- Kernel 1: QKV projection, SPLIT BY MATRIX (grid 768, 3x parallelism) ---------
__global__ __launch_bounds__(256) void qkv_kernel(
    const float* __restrict__ qry, const float* __restrict__ key, const float* __restrict__ val,
    const float* __restrict__ Wq, const float* __restrict__ Wk, const float* __restrict__ Wv,
    u16* __restrict__ qb, u16* __restrict__ kb, u16* __restrict__ vtb) {
  __shared__ float w_lds[64 * 65];
  __shared__ float in_lds[64 * 65];
  __shared__ u16 v_lds[64 * 72];
  const int bid = blockIdx.x;
  const int m = bid >> 8;                // 0=Q, 1=K, 2=V
  const int r8 = bid & 255;
  const int b = r8 >> 6;
  const int lbase = (r8 & 63) << 6;
  const int tid = threadIdx.x;
  const int wv = tid >> 6, ln = tid & 63;

  const float* X = (m == 0) ? qry : (m == 1) ? key : val;
  const float* W = (m == 0) ? Wq : (m == 1) ? Wk : Wv;
  const size_t xbase = ((size_t)(b * LSEQ + lbase)) * DH;
  for (int i = tid; i < 4096; i += 256) {
    w_lds[(i >> 6) * 65 + (i & 63)] = W[i];
    in_lds[(i >> 6) * 65 + (i & 63)] = X[xbase + i];
  }
  __syncthreads();
  for (int rr = 0; rr < 16; ++rr) {
    const int row = wv * 16 + rr;
    float acc = 0.f;
#pragma unroll
    for (int d = 0; d < 64; ++d) acc += in_lds[row * 65 + d] * w_lds[ln * 65 + d];
    const size_t orow = ((size_t)(b * LSEQ + lbase + row)) * DH + ln;
    if (m == 0)      qb[orow] = f2bf(acc * 0.1803368801f); // 1/8*log2(e): exp2(q.k)=e^s
    else if (m == 1) kb[orow] = f2bf(acc);
    else             v_lds[row * 72 + ln] = f2bf(acc);
  }
  if (m == 2) {
    __syncthreads();
    // transposed V write: vtb[b][d][l]
    for (int i = tid; i < 4096; i += 256) {
      const int dd = i >> 6, lc = i & 63;
      vtb[((size_t)(b * DH + dd)) * LSEQ + lbase + lc] = v_lds[lc * 72 + dd];
    }
  }
}

// ---- Kernel 2a: REGISTER-ONLY partial rowsums; K resident across 8 q-tiles ------------
__global__ __launch_bounds__(256, 4) void sums_kernel(
    const u16* __restrict__ qb, const u16* __restrict__ kb,
    float* __restrict__ rows_part) {
  __shared__ float red[4][QB];

  const int bid = xcd_swz(blockIdx.x, 6);          // 512 blocks
  const int qg = bid & (NQG_S - 1);
  const int sl = (bid >> 4) & (NSLICE - 1);
  const int b  = bid >> 7;
  const int c0 = sl * SLW;
  const int tid = threadIdx.x;
  const int w = tid >> 6;
  const int l = tid & 63;
  const int lo = l & 15, g = l >> 4;

  const int cw = w * (SLW / 4);

  bf16x8 kr0[8], kr1[8];
#pragma unroll
  for (int t = 0; t < 8; ++t) {
    const size_t koff = ((size_t)(b * LSEQ + c0 + cw + t * 16 + lo)) * DH + 8 * g;
    kr0[t] = *reinterpret_cast<const bf16x8*>(kb + koff);
    kr1[t] = *reinterpret_cast<const bf16x8*>(kb + koff + 32);
  }

  for (int qi = 0; qi < QTPB_S; ++qi) {
    const int qbase = (qg * QTPB_S + qi) << 5;
    bf16x8 qa0[2], qa1[2];
#pragma unroll
    for (int rt = 0; rt < 2; ++rt) {
      const size_t qoff = ((size_t)(b * LSEQ + qbase + rt * 16 + lo)) * DH + 8 * g;
      qa0[rt] = *reinterpret_cast<const bf16x8*>(qb + qoff);
      qa1[rt] = *reinterpret_cast<const bf16x8*>(qb + qoff + 32);
    }

    float lsum[2][4] = {{0.f, 0.f, 0.f, 0.f}, {0.f, 0.f, 0.f, 0.f}};
#pragma unroll
    for (int t = 0; t < 8; ++t) {
#pragma unroll
      for (int rt = 0; rt < 2; ++rt) {
        f32x4 acc = {0.f, 0.f, 0.f, 0.f};
        acc = __builtin_amdgcn_mfma_f32_16x16x32_bf16(qa0[rt], kr0[t], acc, 0, 0, 0);
        acc = __builtin_amdgcn_mfma_f32_16x16x32_bf16(qa1[rt], kr1[t], acc, 0, 0, 0);
#pragma unroll
        for (int i = 0; i < 4; ++i) lsum[rt][i] += exp2f(acc[i]);
      }
    }
#pragma unroll
    for (int rt = 0; rt < 2; ++rt)
#pragma unroll
      for (int i = 0; i < 4; ++i) {
#pragma unroll
        for (int off = 1; off < 16; off <<= 1)
          lsum[rt][i] += __shfl_xor(lsum[rt][i], off, 64);
      }
    if (lo == 0) {
#pragma unroll
      for (int rt = 0; rt < 2; ++rt)
#pragma unroll
        for (int i = 0; i < 4; ++i) red[w][rt * 16 + 4 * g + i] = lsum[rt][i];
    }
    __syncthreads();
    if (tid < QB)
      rows_part[(size_t)sl * NROW + b * LSEQ + qbase + tid] =
          red[0][tid] + red[1][tid] + red[2][tid] + red[3][tid];
    __syncthreads();                     // red consumed before next q-tile
  }
}

// ---------------- Kernel 2b: rowinv = 1 / sum of slice partials ------------------------
__global__ __launch_bounds__(256) void rinv_kernel(
    const float* __restrict__ rows_part, float* __restrict__ rowinv_g) {
  const int i = blockIdx.x * 256 + threadIdx.x;    // 16384 rows
  float s = 0.f;
#pragma unroll
  for (int sl = 0; sl < NSLICE; ++sl) s += rows_part[(size_t)sl * NROW + i];
  rowinv_g[i] = 1.0f / s;
}

// ---- Kernel 2c: FUSED p-tile -> {PV partials + streaming att write} (R14 structure) ---
__global__ __launch_bounds__(256, 2) void fused_kernel(
    const u16* __restrict__ qb, const u16* __restrict__ kb, const u16* __restrict__ vtb,
    const float* __restrict__ rowinv_g, float* __restrict__ att,
    float* __restrict__ pv_part) {
  __shared__ u16 s_tile[QB * PADT];      // 33,280 B
  __shared__ float s_rinv[QB];

  const int bid = xcd_swz(blockIdx.x, 7);          // 1024 blocks
  const int qg = bid & (NQG_F - 1);
  const int sl = (bid >> 5) & (NSLICE - 1);
  const int b  = bid >> 8;
  const int c0 = sl * SLW;
  const int tid = threadIdx.x;
  const int w = tid >> 6;
  const int l = tid & 63;
  const int lo = l & 15, g = l >> 4;

  const int cw = w * (SLW / 4);
  const int dbase = w * 16;

  // --- preload K (64 VGPR) + V (64 VGPR), block-resident across 4 q-tiles ---
  bf16x8 kr0[8], kr1[8];
#pragma unroll
  for (int t = 0; t < 8; ++t) {
    const size_t koff = ((size_t)(b * LSEQ + c0 + cw + t * 16 + lo)) * DH + 8 * g;
    kr0[t] = *reinterpret_cast<const bf16x8*>(kb + koff);
    kr1[t] = *reinterpret_cast<const bf16x8*>(kb + koff + 32);
  }
  const size_t vrow = ((size_t)(b * DH + dbase + lo)) * LSEQ;
  bf16x8 vr[16];
#pragma unroll
  for (int t = 0; t < 16; ++t)
    vr[t] = *reinterpret_cast<const bf16x8*>(vtb + vrow + c0 + t * 32 + 8 * g);

  for (int qi = 0; qi < QTPB_F; ++qi) {
    const int qbase = (qg * QTPB_F + qi) << 5;
    bf16x8 qa0[2], qa1[2];
#pragma unroll
    for (int rt = 0; rt < 2; ++rt) {
      const size_t qoff = ((size_t)(b * LSEQ + qbase + rt * 16 + lo)) * DH + 8 * g;
      qa0[rt] = *reinterpret_cast<const bf16x8*>(qb + qoff);
      qa1[rt] = *reinterpret_cast<const bf16x8*>(qb + qoff + 32);
    }
    if (tid < QB) s_rinv[tid] = rowinv_g[b * LSEQ + qbase + tid];

    // --- Phase 1: QK^T + exp2 into s_tile ---
#pragma unroll
    for (int t = 0; t < 8; ++t) {
#pragma unroll
      for (int rt = 0; rt < 2; ++rt) {
        f32x4 acc = {0.f, 0.f, 0.f, 0.f};
        acc = __builtin_amdgcn_mfma_f32_16x16x32_bf16(qa0[rt], kr0[t], acc, 0, 0, 0);
        acc = __builtin_amdgcn_mfma_f32_16x16x32_bf16(qa1[rt], kr1[t], acc, 0, 0, 0);
#pragma unroll
        for (int i = 0; i < 4; ++i)
          s_tile[(rt * 16 + 4 * g + i) * PADT + cw + t * 16 + lo] = f2bf(exp2f(acc[i]));
      }
    }
    __syncthreads();                     // s_tile + s_rinv ready

    // --- Phase 2a: PV partials (V register-resident) ---
    f32x4 pv0[2] = {{0.f, 0.f, 0.f, 0.f}, {0.f, 0.f, 0.f, 0.f}};
    f32x4 pv1[2] = {{0.f, 0.f, 0.f, 0.f}, {0.f, 0.f, 0.f, 0.f}};
#pragma unroll
    for (int t = 0; t < 8; ++t) {
#pragma unroll
      for (int rt = 0; rt < 2; ++rt) {
        const bf16x8 pa0 = *reinterpret_cast<const bf16x8*>(
            s_tile + (rt * 16 + lo) * PADT + t * 64 + 8 * g);
        pv0[rt] = __builtin_amdgcn_mfma_f32_16x16x32_bf16(pa0, vr[2 * t], pv0[rt], 0, 0, 0);
        const bf16x8 pa1 = *reinterpret_cast<const bf16x8*>(
            s_tile + (rt * 16 + lo) * PADT + t * 64 + 32 + 8 * g);
        pv1[rt] = __builtin_amdgcn_mfma_f32_16x16x32_bf16(pa1, vr[2 * t + 1], pv1[rt], 0, 0, 0);
      }
    }
#pragma unroll
    for (int rt = 0; rt < 2; ++rt)
#pragma unroll
      for (int i = 0; i < 4; ++i) {
        const int r = rt * 16 + 4 * g + i;
        pv_part[((size_t)sl * NROW + b * LSEQ + qbase + r) * DH + dbase + lo] =
            pv0[rt][i] + pv1[rt][i];
      }

    // --- Phase 2b: streaming normalized att store (32 rows x 128 f32x4 units) ---
    float* attbase = att + ((size_t)(b * LSEQ + qbase)) * LSEQ + c0;
#pragma unroll
    for (int it = 0; it < 16; ++it) {
      const int u = it * 256 + tid;      // 0..4095
      const int row = u >> 7;            // wave-uniform
      const int c4 = (u & 127) * 4;
      const u16x4 p4 = *reinterpret_cast<const u16x4*>(s_tile + row * PADT + c4);
      const float ri = s_rinv[row];
      f32x4 o;
      o[0] = bf2f(p4[0]) * ri; o[1] = bf2f(p4[1]) * ri;
      o[2] = bf2f(p4[2]) * ri; o[3] = bf2f(p4[3]) * ri;
      __builtin_nontemporal_store(o, reinterpret_cast<f32x4*>(attbase + (size_t)row * LSEQ + c4));
    }
    __syncthreads();                     // s_tile/s_rinv consumed
  }
}

// ------- Kernel 3: (sum pv_part)*rinv + residual LN1 -> MLP -> residual LN2 ------------
__global__ __launch_bounds__(256) void post_kernel(
    const float* __restrict__ pv_part, const float* __restrict__ rowinv_g,
    const float* __restrict__ qry,
    const float* __restrict__ ln1g, const float* __restrict__ ln1b,
    const float* __restrict__ W1, const float* __restrict__ b1,
    const float* __restrict__ W2, const float* __restrict__ b2,
    const float* __restrict__ ln2g, const float* __restrict__ ln2b,
    float* __restrict__ out) {
  __shared__ float w1_lds[64 * 65];
  __shared__ float w2_lds[64 * 65];
  __shared__ float vg1[64], vb1l[64], vbi1[64], vbi2[64], vg2[64], vb2l[64];
  __shared__ float o1_buf[4][64];
  __shared__ float h_buf[4][64];
  const int bid = blockIdx.x;
  const int b = bid >> 8;
  const int lbase = (bid & 255) << 4;
  const int tid = threadIdx.x, wv = tid >> 6, ln = tid & 63;

  for (int i = tid; i < 4096; i += 256) {
    w1_lds[(i >> 6) * 65 + (i & 63)] = W1[i];
    w2_lds[(i >> 6) * 65 + (i & 63)] = W2[i];
  }
  if (tid < 64) {
    vg1[tid] = ln1g[tid]; vb1l[tid] = ln1b[tid];
    vbi1[tid] = b1[tid];  vbi2[tid] = b2[tid];
    vg2[tid] = ln2g[tid]; vb2l[tid] = ln2b[tid];
  }
  __syncthreads();

  for (int rr = 0; rr < 4; ++rr) {
    const int row = wv * 4 + rr;
    const size_t rowg = (size_t)b * LSEQ + lbase + row;
    const size_t gr = rowg * DH;
    float x = 0.f;
#pragma unroll
    for (int sl = 0; sl < NSLICE; ++sl) x += pv_part[((size_t)sl * NROW + rowg) * DH + ln];
    x = x * rowinv_g[rowg] + qry[gr + ln];
    float mu = wsum(x) * (1.f / 64.f);
    float dx = x - mu;
    float var = wsum(dx * dx) * (1.f / 64.f);
    const float o1 = dx * rsqrtf(var + 1e-6f) * vg1[ln] + vb1l[ln];
    o1_buf[wv][ln] = o1;
    float a1 = vbi1[ln];
#pragma unroll
    for (int d = 0; d < 64; ++d) a1 += o1_buf[wv][d] * w1_lds[ln * 65 + d];
    const float h = fmaxf(a1, 0.f);
    h_buf[wv][ln] = h;
    float a2 = vbi2[ln];
#pragma unroll
    for (int d = 0; d < 64; ++d) a2 += h_buf[wv][d] * w2_lds[ln * 65 + d];
    const float y = o1 + a2;
    mu = wsum(y) * (1.f / 64.f);
    const float dy = y - mu;
    var = wsum(dy * dy) * (1.f / 64.f);
    out[gr + ln] = dy * rsqrtf(var + 1e-6f) * vg2[ln] + vb2l[ln];
  }
}

extern "C" void kernel_launch(void* const* d_in, const int* in_sizes, int n_in,
                              void* d_out, int out_size, void* d_ws, size_t ws_size,
                              hipStream_t stream) {
  const float* qry = (const float*)d_in[0];
  const float* key = (const float*)d_in[1];
  const float* val = (const float*)d_in[2];
  const float* Wq  = (const float*)d_in[3];
  const float* Wk  = (const float*)d_in[4];
  const float* Wv  = (const float*)d_in[5];
  const float* g1  = (const float*)d_in[6];
  const float* bb1 = (const float*)d_in[7];
  const float* W1  = (const float*)d_in[8];
  const float* b1  = (const float*)d_in[9];
  const float* W2  = (const float*)d_in[10];
  const float* b2  = (const float*)d_in[11];
  const float* g2  = (const float*)d_in[12];
  const float* bb2 = (const float*)d_in[13];

  u16* qb  = (u16*)d_ws;                         // 2 MB
  u16* kb  = qb + (size_t)NROW * DH;             // 2 MB
  u16* vtb = kb + (size_t)NROW * DH;             // 2 MB (transposed [B][D][L])
  float* rows_part = (float*)(vtb + (size_t)NROW * DH);  // 512 KB
  float* rowinv_g  = rows_part + (size_t)NSLICE * NROW;  // 64 KB
  float* pv_part   = rowinv_g + NROW;            // 33.5 MB
  float* out = (float*)d_out;                    // [B,L,D] f32
  float* att = out + (size_t)NROW * DH;          // [B,L,L] f32

  qkv_kernel<<<dim3(768), dim3(256), 0, stream>>>(qry, key, val, Wq, Wk, Wv, qb, kb, vtb);
  sums_kernel<<<dim3(NBATCH * NSLICE * NQG_S), dim3(256), 0, stream>>>(qb, kb, rows_part);
  rinv_kernel<<<dim3(NROW / 256), dim3(256), 0, stream>>>(rows_part, rowinv_g);
  fused_kernel<<<dim3(NBATCH * NSLICE * NQG_F), dim3(256), 0, stream>>>(
      qb, kb, vtb, rowinv_g, att, pv_part);
  post_kernel<<<dim3(NBATCH * 256), dim3(256), 0, stream>>>(
      pv_part, rowinv_g, qry, g1, bb1, W1, b1, W2, b2, g2, bb2, out);
}